// Round 16
// baseline (123.206 us; speedup 1.0000x reference)
//
#include <hip/hip_runtime.h>
#include <hip/hip_fp16.h>

// Problem constants (reference: B,N,D,H,C = 4,512,128,128,3)
#define B_ 4
#define N_ 512
#define D_ 128
#define H_ 128
#define C_ 3

#define NEG_LOG2E   (-1.4426950408889634f)
#define NEG_HALF_LN2 (-0.34657359027997264f)   // -0.5 * ln(2)
#define TPAD 132   // j-tile f16 row stride: 264 B -> row bank offset 2, conflict-free reads

typedef _Float16 half8  __attribute__((ext_vector_type(8)));
typedef _Float16 half4v __attribute__((ext_vector_type(4)));
typedef _Float16 half2v __attribute__((ext_vector_type(2)));
typedef __fp16   fp16v2 __attribute__((ext_vector_type(2)));   // builtin arg/ret type

__device__ __forceinline__ float exp2_fast(float x) {
    return __builtin_amdgcn_exp2f(x);   // raw v_exp_f32 (2^x)
}

// Projections stored PRE-SCALED by -log2e in f16, PLUS their exp2 in f16:
//   At[row][h] = f16(-log2e * (dot(h[row], W1[h][0:128]) + b1[h]))   EAt = 2^At
//   Bt[row][h] = f16(-log2e *  dot(h[row], W1[h][128:256]))          EBt = 2^Bt
// Block (0,0) additionally converts W2 to f16 (W2h, 384 elems).
__global__ __launch_bounds__(256) void proj_gemm(
    const float* __restrict__ hd, const float* __restrict__ W1,
    const float* __restrict__ b1, const float* __restrict__ W2,
    _Float16* __restrict__ At,  _Float16* __restrict__ Bt,
    _Float16* __restrict__ EAt, _Float16* __restrict__ EBt,
    _Float16* __restrict__ W2h)
{
    __shared__ float hsT[64][36];   // [k][m]
    __shared__ float wt [64][68];   // [k][o]
    const int m0      = blockIdx.x * 32;
    const int by      = blockIdx.y;        // 0..3
    const int halfSel = by >> 1;           // 0 -> At, 1 -> Bt
    const int wrow0   = (by & 1) * 64;     // W1 row base (== output h-col base)

    const int t  = threadIdx.x;
    const int r  = t >> 4, c4 = t & 15;
    const int tx = t & 15, ty = t >> 4;

    if (blockIdx.x == 0 && by == 0) {      // one-time W2 -> f16
        for (int u = t; u < C_ * H_; u += 256) W2h[u] = (_Float16)W2[u];
    }

    float acc[2][4] = {};

    for (int kc = 0; kc < 2; ++kc) {
        if (kc) __syncthreads();
        #pragma unroll
        for (int i = 0; i < 2; ++i) {
            const int m = r + 16 * i;
            float4 v = *(const float4*)&hd[(m0 + m) * D_ + kc * 64 + 4 * c4];
            hsT[4 * c4 + 0][m] = v.x; hsT[4 * c4 + 1][m] = v.y;
            hsT[4 * c4 + 2][m] = v.z; hsT[4 * c4 + 3][m] = v.w;
        }
        #pragma unroll
        for (int i = 0; i < 4; ++i) {
            const int o = r + 16 * i;
            float4 v = *(const float4*)&W1[(wrow0 + o) * (2 * D_) + halfSel * D_ + kc * 64 + 4 * c4];
            wt[4 * c4 + 0][o] = v.x; wt[4 * c4 + 1][o] = v.y;
            wt[4 * c4 + 2][o] = v.z; wt[4 * c4 + 3][o] = v.w;
        }
        __syncthreads();
        #pragma unroll 8
        for (int k = 0; k < 64; ++k) {
            float2 a  = *(const float2*)&hsT[k][2 * ty];
            float4 bv = *(const float4*)&wt [k][4 * tx];
            acc[0][0] = fmaf(a.x, bv.x, acc[0][0]); acc[0][1] = fmaf(a.x, bv.y, acc[0][1]);
            acc[0][2] = fmaf(a.x, bv.z, acc[0][2]); acc[0][3] = fmaf(a.x, bv.w, acc[0][3]);
            acc[1][0] = fmaf(a.y, bv.x, acc[1][0]); acc[1][1] = fmaf(a.y, bv.y, acc[1][1]);
            acc[1][2] = fmaf(a.y, bv.z, acc[1][2]); acc[1][3] = fmaf(a.y, bv.w, acc[1][3]);
        }
    }

    _Float16* dst  = halfSel ? Bt  : At;
    _Float16* edst = halfSel ? EBt : EAt;
    const int ocol = wrow0 + 4 * tx;
    float biasv[4] = {0.f, 0.f, 0.f, 0.f};
    if (!halfSel) {
        float4 bb = *(const float4*)&b1[ocol];
        biasv[0] = bb.x; biasv[1] = bb.y; biasv[2] = bb.z; biasv[3] = bb.w;
    }
    #pragma unroll
    for (int i = 0; i < 2; ++i) {
        half4v o, ee;
        #pragma unroll
        for (int k = 0; k < 4; ++k) {
            o[k]  = (_Float16)((acc[i][k] + biasv[k]) * NEG_LOG2E);
            ee[k] = (_Float16)exp2_fast((float)o[k]);
        }
        const size_t off = (size_t)(m0 + 2 * ty + i) * H_ + ocol;
        *(half4v*)&dst[off]  = o;
        *(half4v*)&edst[off] = ee;
    }
}

// One 128-thread block per (batch, upper-tri 16x16 tile pair); 2112 blocks.
// Thread (ti,tj), ti=0..7, tj=0..15 owns pairs (I0+ti, J0+tj) and (I0+ti+8,
// J0+tj). J-tile (y/e, A/B) staged whole in LDS (16.9 KB, pad-132 ->
// conflict-free); i-side read per chunk straight from global into registers
// (16-lane-uniform addresses -> L1 broadcast) with explicit next-chunk
// prefetch. Exp-factorized pk-f16 math + v_dot2_f32_f16 W2 contraction.
__global__ __launch_bounds__(128, 3) void pair_kernel(
    const _Float16* __restrict__ At,  const _Float16* __restrict__ Bt,
    const _Float16* __restrict__ EAt, const _Float16* __restrict__ EBt,
    const _Float16* __restrict__ W2h, const float* __restrict__ b2,
    float* __restrict__ out)
{
    __shared__ __align__(16) _Float16 jt[4][16 * TPAD];   // yA, yB, eA, eB (J rows)
    const int b = blockIdx.y;
    int tp = blockIdx.x;
    int I = 0;
    while (tp >= 32 - I) { tp -= 32 - I; ++I; }   // uniform decode, T=32
    const int J = I + tp;

    const int tid = threadIdx.x;
    // stage J-tile: 4 arrays x 16 rows x 16 chunks = 1024 half8, 8 per thread
    #pragma unroll
    for (int k = 0; k < 8; ++k) {
        const int u   = tid + 128 * k;
        const int tl  = u >> 8;            // 0..3
        const int row = (u >> 4) & 15;
        const int c   = u & 15;
        const _Float16* src = (tl == 0) ? At : (tl == 1) ? Bt : (tl == 2) ? EAt : EBt;
        half8 v = *(const half8*)&src[((size_t)(b * N_) + J * 16 + row) * H_ + c * 8];
        *(half8*)&jt[tl][row * TPAD + c * 8] = v;
    }
    __syncthreads();

    const int tj = tid & 15, ti = tid >> 4;   // ti 0..7
    const int iA = I * 16 + ti, iB = iA + 8;
    const size_t ibA = ((size_t)(b * N_) + iA) * H_;
    const size_t ibB = ((size_t)(b * N_) + iB) * H_;

    float accA0 = 0.f, accA1 = 0.f, accA2 = 0.f;
    float accB0 = 0.f, accB1 = 0.f, accB2 = 0.f;

    #define LD(P, base, ch) (*(const half8*)&P[(base) + (ch) * 8])
    // prefetch chunk 0 i-side
    half8 cyA0 = LD(At, ibA, 0), cyB0 = LD(Bt, ibA, 0);
    half8 ceA0 = LD(EAt, ibA, 0), ceB0 = LD(EBt, ibA, 0);
    half8 cyA1 = LD(At, ibB, 0), cyB1 = LD(Bt, ibB, 0);
    half8 ceA1 = LD(EAt, ibB, 0), ceB1 = LD(EBt, ibB, 0);

    #pragma unroll
    for (int ch = 0; ch < 16; ++ch) {
        half8 nyA0, nyB0, neA0, neB0, nyA1, nyB1, neA1, neB1;
        if (ch < 15) {   // compile-time predicate (full unroll)
            nyA0 = LD(At, ibA, ch + 1); nyB0 = LD(Bt, ibA, ch + 1);
            neA0 = LD(EAt, ibA, ch + 1); neB0 = LD(EBt, ibA, ch + 1);
            nyA1 = LD(At, ibB, ch + 1); nyB1 = LD(Bt, ibB, ch + 1);
            neA1 = LD(EAt, ibB, ch + 1); neB1 = LD(EBt, ibB, ch + 1);
        }
        const int jo = tj * TPAD + ch * 8;
        const half8 yAj = *(const half8*)&jt[0][jo];
        const half8 yBj = *(const half8*)&jt[1][jo];
        const half8 eAj = *(const half8*)&jt[2][jo];
        const half8 eBj = *(const half8*)&jt[3][jo];

        const int hb = ch * 8;
        const half8 w0 = *(const half8*)&W2h[0 * H_ + hb];
        const half8 w1 = *(const half8*)&W2h[1 * H_ + hb];
        const half8 w2 = *(const half8*)&W2h[2 * H_ + hb];
        const fp16v2* w0q = (const fp16v2*)&w0;
        const fp16v2* w1q = (const fp16v2*)&w1;
        const fp16v2* w2q = (const fp16v2*)&w2;

        #define PAIRM(a0, a1, a2, yAi, yBi, eAi, eBi)                             \
        {                                                                         \
            half8 y1 = (yAi) + yBj;                    /* v_pk_add_f16 */         \
            half8 y2 = yAj + (yBi);                                               \
            half8 e1 = (eAi) * eBj;                    /* v_pk_mul_f16 */         \
            half8 e2 = eAj * (eBi);                                               \
            half8 d1 = e1 + (_Float16)1.0f;                                       \
            half8 d2 = e2 + (_Float16)1.0f;                                       \
            half8 pp  = d1 * d2;                                                  \
            half8 num = y1 * d2 + y2 * d1;             /* pk_mul + pk_fma */      \
            const half2v* num2 = (const half2v*)&num;                             \
            _Pragma("unroll")                                                     \
            for (int q = 0; q < 4; ++q) {                                         \
                const float r0 = __builtin_amdgcn_rcpf((float)pp[2 * q]);         \
                const float r1 = __builtin_amdgcn_rcpf((float)pp[2 * q + 1]);     \
                fp16v2 rr = __builtin_amdgcn_cvt_pkrtz(r0, r1);                   \
                half2v s2 = num2[q] * __builtin_bit_cast(half2v, rr);             \
                fp16v2 sv = __builtin_bit_cast(fp16v2, s2);                       \
                a0 = __builtin_amdgcn_fdot2(sv, w0q[q], a0, false);               \
                a1 = __builtin_amdgcn_fdot2(sv, w1q[q], a1, false);               \
                a2 = __builtin_amdgcn_fdot2(sv, w2q[q], a2, false);               \
            }                                                                     \
        }
        PAIRM(accA0, accA1, accA2, cyA0, cyB0, ceA0, ceB0)
        PAIRM(accB0, accB1, accB2, cyA1, cyB1, ceA1, ceB1)
        #undef PAIRM

        cyA0 = nyA0; cyB0 = nyB0; ceA0 = neA0; ceB0 = neB0;
        cyA1 = nyA1; cyB1 = nyB1; ceA1 = neA1; ceB1 = neB1;
    }
    #undef LD

    const float b20 = b2[0], b21 = b2[1], b22 = b2[2];
    const int j = J * 16 + tj;
    {
        const float o0 = fmaf(NEG_HALF_LN2, accA0, b20);
        const float o1 = fmaf(NEG_HALF_LN2, accA1, b21);
        const float o2 = fmaf(NEG_HALF_LN2, accA2, b22);
        float* p1 = out + ((size_t)(b * N_ + iA) * N_ + j) * C_;
        float* p2 = out + ((size_t)(b * N_ + j) * N_ + iA) * C_;
        p1[0] = o0; p1[1] = o1; p1[2] = o2;
        p2[0] = o0; p2[1] = o1; p2[2] = o2;
    }
    {
        const float o0 = fmaf(NEG_HALF_LN2, accB0, b20);
        const float o1 = fmaf(NEG_HALF_LN2, accB1, b21);
        const float o2 = fmaf(NEG_HALF_LN2, accB2, b22);
        float* p1 = out + ((size_t)(b * N_ + iB) * N_ + j) * C_;
        float* p2 = out + ((size_t)(b * N_ + j) * N_ + iB) * C_;
        p1[0] = o0; p1[1] = o1; p1[2] = o2;
        p2[0] = o0; p2[1] = o1; p2[2] = o2;
    }
}

extern "C" void kernel_launch(void* const* d_in, const int* in_sizes, int n_in,
                              void* d_out, int out_size, void* d_ws, size_t ws_size,
                              hipStream_t stream) {
    const float* hd = (const float*)d_in[0];
    const float* W1 = (const float*)d_in[1];
    const float* b1 = (const float*)d_in[2];
    const float* W2 = (const float*)d_in[3];
    const float* b2 = (const float*)d_in[4];
    float* out = (float*)d_out;

    _Float16* At  = (_Float16*)d_ws;             // 4 x [B*N][H] f16 = 2 MiB + W2h 768 B
    _Float16* Bt  = At  + B_ * N_ * H_;
    _Float16* EAt = Bt  + B_ * N_ * H_;
    _Float16* EBt = EAt + B_ * N_ * H_;
    _Float16* W2h = EBt + B_ * N_ * H_;

    proj_gemm<<<dim3((B_ * N_) / 32, 4), dim3(256), 0, stream>>>(
        hd, W1, b1, W2, At, Bt, EAt, EBt, W2h);

    // 528 upper-tri 16x16 tile pairs x 4 batches = 2112 blocks of 128 threads
    pair_kernel<<<dim3(528, B_), dim3(128), 0, stream>>>(At, Bt, EAt, EBt, W2h, b2, out);
}

// Round 17
// 57.123 us; speedup vs baseline: 2.1568x; 2.1568x over previous
//
#include <hip/hip_runtime.h>
#include <hip/hip_fp16.h>

// Problem constants (reference: B,N,D,H,C = 4,512,128,128,3)
#define B_ 4
#define N_ 512
#define D_ 128
#define H_ 128
#define C_ 3

#define NEG_LOG2E   (-1.4426950408889634f)
#define NEG_HALF_LN2 (-0.34657359027997264f)   // -0.5 * ln(2)
#define TPAD 132   // j-tile f16 row stride: 264 B -> per-row bank offset 2 -> conflict-free

typedef _Float16 half8  __attribute__((ext_vector_type(8)));
typedef _Float16 half4v __attribute__((ext_vector_type(4)));

__device__ __forceinline__ float exp2_fast(float x) {
    return __builtin_amdgcn_exp2f(x);   // raw v_exp_f32 (2^x)
}

// Projections stored PRE-SCALED by -log2e in f16, PLUS their exp2 in f16:
//   At[row][h] = f16(-log2e * (dot(h[row], W1[h][0:128]) + b1[h]))   EAt = 2^At
//   Bt[row][h] = f16(-log2e *  dot(h[row], W1[h][128:256]))          EBt = 2^Bt
__global__ __launch_bounds__(256) void proj_gemm(
    const float* __restrict__ hd, const float* __restrict__ W1,
    const float* __restrict__ b1,
    _Float16* __restrict__ At,  _Float16* __restrict__ Bt,
    _Float16* __restrict__ EAt, _Float16* __restrict__ EBt)
{
    __shared__ float hsT[64][36];   // [k][m]
    __shared__ float wt [64][68];   // [k][o]
    const int m0      = blockIdx.x * 32;
    const int by      = blockIdx.y;        // 0..3
    const int halfSel = by >> 1;           // 0 -> At, 1 -> Bt
    const int wrow0   = (by & 1) * 64;     // W1 row base (== output h-col base)

    const int t  = threadIdx.x;
    const int r  = t >> 4, c4 = t & 15;
    const int tx = t & 15, ty = t >> 4;

    float acc[2][4] = {};

    for (int kc = 0; kc < 2; ++kc) {
        if (kc) __syncthreads();
        #pragma unroll
        for (int i = 0; i < 2; ++i) {
            const int m = r + 16 * i;
            float4 v = *(const float4*)&hd[(m0 + m) * D_ + kc * 64 + 4 * c4];
            hsT[4 * c4 + 0][m] = v.x; hsT[4 * c4 + 1][m] = v.y;
            hsT[4 * c4 + 2][m] = v.z; hsT[4 * c4 + 3][m] = v.w;
        }
        #pragma unroll
        for (int i = 0; i < 4; ++i) {
            const int o = r + 16 * i;
            float4 v = *(const float4*)&W1[(wrow0 + o) * (2 * D_) + halfSel * D_ + kc * 64 + 4 * c4];
            wt[4 * c4 + 0][o] = v.x; wt[4 * c4 + 1][o] = v.y;
            wt[4 * c4 + 2][o] = v.z; wt[4 * c4 + 3][o] = v.w;
        }
        __syncthreads();
        #pragma unroll 8
        for (int k = 0; k < 64; ++k) {
            float2 a  = *(const float2*)&hsT[k][2 * ty];
            float4 bv = *(const float4*)&wt [k][4 * tx];
            acc[0][0] = fmaf(a.x, bv.x, acc[0][0]); acc[0][1] = fmaf(a.x, bv.y, acc[0][1]);
            acc[0][2] = fmaf(a.x, bv.z, acc[0][2]); acc[0][3] = fmaf(a.x, bv.w, acc[0][3]);
            acc[1][0] = fmaf(a.y, bv.x, acc[1][0]); acc[1][1] = fmaf(a.y, bv.y, acc[1][1]);
            acc[1][2] = fmaf(a.y, bv.z, acc[1][2]); acc[1][3] = fmaf(a.y, bv.w, acc[1][3]);
        }
    }

    _Float16* dst  = halfSel ? Bt  : At;
    _Float16* edst = halfSel ? EBt : EAt;
    const int ocol = wrow0 + 4 * tx;
    float biasv[4] = {0.f, 0.f, 0.f, 0.f};
    if (!halfSel) {
        float4 bb = *(const float4*)&b1[ocol];
        biasv[0] = bb.x; biasv[1] = bb.y; biasv[2] = bb.z; biasv[3] = bb.w;
    }
    #pragma unroll
    for (int i = 0; i < 2; ++i) {
        half4v o, ee;
        #pragma unroll
        for (int k = 0; k < 4; ++k) {
            o[k]  = (_Float16)((acc[i][k] + biasv[k]) * NEG_LOG2E);
            ee[k] = (_Float16)exp2_fast((float)o[k]);   // E = 2^y, consistent with y_f16
        }
        const size_t off = (size_t)(m0 + 2 * ty + i) * H_ + ocol;
        *(half4v*)&dst[off]  = o;
        *(half4v*)&edst[off] = ee;
    }
}

// r9 structure with ONE change: i-side moved off the LDS pipe. One 256-thread
// block per (batch, upper-tri 16x16 tile pair), 2112 blocks. J-side y/e tiles
// staged whole in LDS (4 x [16][TPAD] f16 = 16.9 KB, one sync); i-side read
// per chunk directly from global (16 lanes share each address -> L1 broadcast;
// 16 KB working set per block, L1-resident). LDS reads/chunk: 8 -> 4.
// Exp-factorized pk-f16 math (e^(yi+yj) = Ei*Ej), shared f32 rcp per pair-h.
__global__ __launch_bounds__(256, 4) void pair_kernel(
    const _Float16* __restrict__ At,  const _Float16* __restrict__ Bt,
    const _Float16* __restrict__ EAt, const _Float16* __restrict__ EBt,
    const float* __restrict__ W2, const float* __restrict__ b2,
    float* __restrict__ out)
{
    __shared__ __align__(16) _Float16 jt[4][16 * TPAD];   // yA, yB, eA, eB (J-tile rows)
    const int b = blockIdx.y;
    int tp = blockIdx.x;
    int I = 0;
    while (tp >= 32 - I) { tp -= 32 - I; ++I; }   // uniform decode, T=32
    const int J = I + tp;

    const int tid = threadIdx.x;
    // stage J-tile: 4 arrays x 16 rows x 16 chunks = 1024 half8, 4 per thread
    #pragma unroll
    for (int k = 0; k < 4; ++k) {
        const int u   = tid + 256 * k;
        const int tl  = u >> 8;            // 0..3
        const int row = (u >> 4) & 15;
        const int c   = u & 15;
        const _Float16* src = (tl == 0) ? At : (tl == 1) ? Bt : (tl == 2) ? EAt : EBt;
        half8 v = *(const half8*)&src[((size_t)(b * N_) + J * 16 + row) * H_ + c * 8];
        *(half8*)&jt[tl][row * TPAD + c * 8] = v;
    }
    __syncthreads();

    const int ti = tid >> 4, tj = tid & 15;
    const int i = I * 16 + ti, j = J * 16 + tj;
    const size_t ibase = ((size_t)(b * N_) + i) * H_;   // same for 16 lanes -> broadcast

    float acc0 = 0.f, acc1 = 0.f, acc2 = 0.f;

    #pragma unroll 4
    for (int ch = 0; ch < 16; ++ch) {
        const int hb = ch * 8;
        // i-side: 4 global b128 loads, 16-lane-uniform address (L1 broadcast)
        const half8 yAi = *(const half8*)&At [ibase + hb];
        const half8 yBi = *(const half8*)&Bt [ibase + hb];
        const half8 eAi = *(const half8*)&EAt[ibase + hb];
        const half8 eBi = *(const half8*)&EBt[ibase + hb];
        // j-side: 4 LDS b128 reads, conflict-free (pad-132)
        const int jo = tj * TPAD + hb;
        const half8 yAj = *(const half8*)&jt[0][jo];
        const half8 yBj = *(const half8*)&jt[1][jo];
        const half8 eAj = *(const half8*)&jt[2][jo];
        const half8 eBj = *(const half8*)&jt[3][jo];

        half8 y1 = yAi + yBj;                    // v_pk_add_f16
        half8 y2 = yAj + yBi;
        half8 e1 = eAi * eBj;                    // v_pk_mul_f16
        half8 e2 = eAj * eBi;
        half8 d1 = e1 + (_Float16)1.0f;
        half8 d2 = e2 + (_Float16)1.0f;
        half8 pp  = d1 * d2;
        half8 num = y1 * d2 + y2 * d1;           // pk_mul + pk_fma

        // W2: uniform scalar loads
        float4 w0a = *(const float4*)&W2[hb],          w0b = *(const float4*)&W2[hb + 4];
        float4 w1a = *(const float4*)&W2[H_ + hb],     w1b = *(const float4*)&W2[H_ + hb + 4];
        float4 w2a = *(const float4*)&W2[2 * H_ + hb], w2b = *(const float4*)&W2[2 * H_ + hb + 4];
        const float w0[8] = {w0a.x, w0a.y, w0a.z, w0a.w, w0b.x, w0b.y, w0b.z, w0b.w};
        const float w1[8] = {w1a.x, w1a.y, w1a.z, w1a.w, w1b.x, w1b.y, w1b.z, w1b.w};
        const float w2[8] = {w2a.x, w2a.y, w2a.z, w2a.w, w2b.x, w2b.y, w2b.z, w2b.w};

        #pragma unroll
        for (int e = 0; e < 8; ++e) {
            const float s = (float)num[e] * __builtin_amdgcn_rcpf((float)pp[e]);
            acc0 = fmaf(s, w0[e], acc0);
            acc1 = fmaf(s, w1[e], acc1);
            acc2 = fmaf(s, w2[e], acc2);
        }
    }

    const float o0 = fmaf(NEG_HALF_LN2, acc0, b2[0]);
    const float o1 = fmaf(NEG_HALF_LN2, acc1, b2[1]);
    const float o2 = fmaf(NEG_HALF_LN2, acc2, b2[2]);
    float* p1 = out + ((size_t)(b * N_ + i) * N_ + j) * C_;
    float* p2 = out + ((size_t)(b * N_ + j) * N_ + i) * C_;
    p1[0] = o0; p1[1] = o1; p1[2] = o2;
    p2[0] = o0; p2[1] = o1; p2[2] = o2;   // diagonal tiles: bit-identical duplicate, benign
}

extern "C" void kernel_launch(void* const* d_in, const int* in_sizes, int n_in,
                              void* d_out, int out_size, void* d_ws, size_t ws_size,
                              hipStream_t stream) {
    const float* hd = (const float*)d_in[0];
    const float* W1 = (const float*)d_in[1];
    const float* b1 = (const float*)d_in[2];
    const float* W2 = (const float*)d_in[3];
    const float* b2 = (const float*)d_in[4];
    float* out = (float*)d_out;

    _Float16* At  = (_Float16*)d_ws;             // 4 x [B*N][H] f16 = 2 MiB total
    _Float16* Bt  = At  + B_ * N_ * H_;
    _Float16* EAt = Bt  + B_ * N_ * H_;
    _Float16* EBt = EAt + B_ * N_ * H_;

    proj_gemm<<<dim3((B_ * N_) / 32, 4), dim3(256), 0, stream>>>(hd, W1, b1, At, Bt, EAt, EBt);

    // 528 upper-tri 16x16 tile pairs x 4 batches = 2112 blocks of 256 threads
    pair_kernel<<<dim3(528, B_), dim3(256), 0, stream>>>(At, Bt, EAt, EBt, W2, b2, out);
}